// Round 9
// baseline (302.733 us; speedup 1.0000x reference)
//
#include <hip/hip_runtime.h>
#include <hip/hip_bf16.h>

// Attention forward, MI355X (gfx950). fp32 in/out, bf16 MFMA internally.
// ws (56 MB): wqkv_b[3072x1024 bf16] | wo_b[1024x1024 bf16] | QKV[8192x3072 bf16]
// xb (bf16 x) lives in d_out's first 16 MB (dead before out-proj writes).
// Dispatches: 1 fused convert; QKV GEMM; flash; out-proj GEMM.
// MFMA layouts (verified m89/m74):
//   A-frag: A[m=lane&15][k=(lane>>4)*8+j]; B-frag: B[n=lane&15][k=...]
//   C/D:    col=lane&15, row=(lane>>4)*4+reg
//
// Round-8:  both-sides LDS swizzles in flash. Conflicts 1.62e7->6.5e6, dur flat.
// Round-9:  lgkm-only barrier in flash. 163->157 us.
// Round-10: K LDS-staged (pre-swizzled source) + XCD grouping in flash.
//           FETCH 240->38 MB, flash 157->89.6 us. Latency theory confirmed.
// Round-11: GEMM XCD remap + BK=64 swizzled staging + fused converts. 280->262.
// Round-12: fused pair p-loop: np non-uniform per CU -> 105 us. REVERTED.
// Round-13: ones-MFMA l-sum + setprio: flash 86.3, VGPR 84.
// Round-14: gemm3 (128x256 3-buf counted vmcnt): total 251.0.
// Round-15: gemm2p (128^2 2-buf counted vmcnt): 253.3 ~= gemm3. GEMM coarse
//           restructures are noise-level; stopped.
// Round-16 (this): flash DS-pipe analysis: per wave-iter ~264 DS cyc; 132
//   block-iters x4 waves x264 = 139K cyc vs 206K wall = 68% DS busy (and the
//   same model reproduces VALUBusy 42%) -> flash is LDS-ISSUE-BOUND.
//   Fix: 32 q-rows/wave (two 16-row sets). ka/kb read once feeds both sets'
//   QK; vb read once (per kc,c) feeds both sets' PV -> DS/q-row 16.5->9.5 cyc.
//   Block = q-tile 128, pair (QB,15-QB) passes -> np uniform 34. Grid 512
//   (2 blocks/CU), same XCD grouping, same sync skeleton/staging as R4.

typedef short short8 __attribute__((ext_vector_type(8)));
typedef float f32x4 __attribute__((ext_vector_type(4)));

#define MFMA16(a, b, c) __builtin_amdgcn_mfma_f32_16x16x32_bf16((a), (b), (c), 0, 0, 0)

static __device__ __forceinline__ ushort f2bf(float f) {
  union { __hip_bfloat16 h; ushort u; } cv;
  cv.h = __float2bfloat16(f);
  return cv.u;
}

static __device__ __forceinline__ float fexp2(float x) {
#if __has_builtin(__builtin_amdgcn_exp2f)
  return __builtin_amdgcn_exp2f(x);
#else
  return __expf(x * 0.69314718056f);
#endif
}

// Barrier WITHOUT any vmcnt drain: LDS writes visible, globals keep flying.
static __device__ __forceinline__ void block_sync_lds() {
  asm volatile("s_waitcnt lgkmcnt(0)" ::: "memory");
  __builtin_amdgcn_s_barrier();
  __builtin_amdgcn_sched_barrier(0);
}

// Barrier that ALSO waits outstanding globals (global_load_lds visibility).
static __device__ __forceinline__ void block_sync_full() {
  asm volatile("s_waitcnt vmcnt(0) lgkmcnt(0)" ::: "memory");
  __builtin_amdgcn_s_barrier();
  __builtin_amdgcn_sched_barrier(0);
}

static __device__ __forceinline__ void store_out(float* p, float v) { *p = v; }
static __device__ __forceinline__ void store_out(__hip_bfloat16* p, float v) {
  *p = __float2bfloat16(v);
}

// One fused convert: wq|wk|wv -> wqkv_b rows, wo -> wo_b, x -> xb.
__global__ __launch_bounds__(256) void convert_all_kernel(
    const float* __restrict__ wq, const float* __restrict__ wk,
    const float* __restrict__ wv, const float* __restrict__ wo,
    const float* __restrict__ x, ushort* __restrict__ wqkv,
    ushort* __restrict__ wob, ushort* __restrict__ xb) {
  constexpr int W4 = 262144;           // (1024*1024)/4
  constexpr size_t WSZ = (size_t)1024 * 1024;
  const int i = blockIdx.x * blockDim.x + threadIdx.x;
  const float* src;
  ushort* dst;
  int j;
  if (i < 2 * W4) {
    if (i < W4)      { src = wq; dst = wqkv;           j = i; }
    else             { src = wk; dst = wqkv + WSZ;     j = i - W4; }
  } else if (i < 4 * W4) {
    if (i < 3 * W4)  { src = wv; dst = wqkv + 2 * WSZ; j = i - 2 * W4; }
    else             { src = wo; dst = wob;            j = i - 3 * W4; }
  } else {
    src = x; dst = xb; j = i - 4 * W4;
  }
  const float4 v = ((const float4*)src)[j];
  ushort4 o;
  o.x = f2bf(v.x); o.y = f2bf(v.y); o.z = f2bf(v.z); o.w = f2bf(v.w);
  ((ushort4*)dst)[j] = o;
}

// ---------------- 2-buffer pipelined 128x128 GEMM (gemm2p) ----------------
// C[M,N] = A[M,K](bf16) * B[N,K]^T(bf16), OUT_T out. BK=64, 4 waves,
// wave tile 64x64 (4x4 frags), 2 LDS buffers (64 KB -> 2 blocks/CU).
// Counted vmcnt schedule; pre-swizzled-source gload_lds staging (rule 21).
template <typename OUT_T>
__global__ __launch_bounds__(256, 2) void gemm_kernel(
    const ushort* __restrict__ A, int lda, const ushort* __restrict__ B, int ldb,
    OUT_T* __restrict__ C, int ldc, int K, int cpx) {
  __shared__ __align__(16) ushort As[2][128 * 64];
  __shared__ __align__(16) ushort Bs[2][128 * 64];
  const int tid = threadIdx.x;
  const int wave = tid >> 6, lane = tid & 63;
  const int lm = lane & 15, quad = lane >> 4;

  const int id = blockIdx.x;
  const int local = id >> 3;
  const int nt = (id & 7) * cpx + local % cpx;
  const int mt = local / cpx;
  const size_t m0 = (size_t)mt * 128;
  const size_t n0 = (size_t)nt * 128;

  const int rl = lane >> 3;        // row within 8-row staging chunk
  const int cs = (lane & 7) ^ rl;  // pre-swizzled source col-chunk
  const int fsw = lm & 7;          // fragment read swizzle key
  const int wm = (wave >> 1) * 64, wn = (wave & 1) * 64;
  const int T = K >> 6;

  // prologue: stage tile 0 -> buf 0 (8 loads/wave)
#pragma unroll
  for (int j = 0; j < 4; ++j) {
    const int ch = wave * 4 + j;
    __builtin_amdgcn_global_load_lds(
        (const __attribute__((address_space(1))) void*)(B + (n0 + ch * 8 + rl) * (size_t)ldb + cs * 8),
        (__attribute__((address_space(3))) void*)(Bs[0] + ch * 512), 16, 0, 0);
    __builtin_amdgcn_global_load_lds(
        (const __attribute__((address_space(1))) void*)(A + (m0 + ch * 8 + rl) * (size_t)lda + cs * 8),
        (__attribute__((address_space(3))) void*)(As[0] + ch * 512), 16, 0, 0);
  }

  f32x4 acc[4][4] = {};
  for (int t = 0; t < T; ++t) {
    const int cur = t & 1;
    if (t + 1 < T) {
      const int k0 = (t + 1) << 6;
      ushort* an = As[cur ^ 1];
      ushort* bn = Bs[cur ^ 1];
#pragma unroll
      for (int j = 0; j < 4; ++j) {
        const int ch = wave * 4 + j;
        __builtin_amdgcn_global_load_lds(
            (const __attribute__((address_space(1))) void*)(B + (n0 + ch * 8 + rl) * (size_t)ldb + k0 + cs * 8),
            (__attribute__((address_space(3))) void*)(bn + ch * 512), 16, 0, 0);
        __builtin_amdgcn_global_load_lds(
            (const __attribute__((address_space(1))) void*)(A + (m0 + ch * 8 + rl) * (size_t)lda + k0 + cs * 8),
            (__attribute__((address_space(3))) void*)(an + ch * 512), 16, 0, 0);
      }
      asm volatile("s_waitcnt vmcnt(8)" ::: "memory");
    } else {
      asm volatile("s_waitcnt vmcnt(0)" ::: "memory");
    }
    __builtin_amdgcn_s_barrier();       // barrier1: tile t visible to all
    __builtin_amdgcn_sched_barrier(0);

    short8 a[4][2], b[4][2];
    const ushort* ab = As[cur];
    const ushort* bb = Bs[cur];
#pragma unroll
    for (int i = 0; i < 4; ++i) {
      const ushort* ar = ab + (wm + i * 16 + lm) * 64;
      const ushort* br = bb + (wn + i * 16 + lm) * 64;
#pragma unroll
      for (int ks = 0; ks < 2; ++ks) {
        const int off = (((ks * 4 + quad) ^ fsw) & 7) << 3;
        a[i][ks] = *(const short8*)(ar + off);
        b[i][ks] = *(const short8*)(br + off);
      }
    }
    asm volatile("s_waitcnt lgkmcnt(0)" ::: "memory");
    __builtin_amdgcn_s_barrier();       // barrier2: all reads done
    __builtin_amdgcn_sched_barrier(0);

    __builtin_amdgcn_s_setprio(1);
#pragma unroll
    for (int i = 0; i < 4; ++i)
#pragma unroll
      for (int j = 0; j < 4; ++j)
#pragma unroll
        for (int ks = 0; ks < 2; ++ks)
          acc[i][j] = MFMA16(a[i][ks], b[j][ks], acc[i][j]);
    __builtin_amdgcn_s_setprio(0);
  }

  const int rq = quad * 4;
#pragma unroll
  for (int i = 0; i < 4; ++i)
#pragma unroll
    for (int j = 0; j < 4; ++j)
#pragma unroll
      for (int r = 0; r < 4; ++r)
        store_out(&C[(m0 + wm + i * 16 + rq + r) * (size_t)ldc + n0 + wn + j * 16 + lm],
                  acc[i][j][r]);
}

// Swizzled V^T LDS write: 8 cols starting at h0 for row p.
// Element (p, h) lives at h*64 + (((p>>3) ^ (h>>3) ^ (h&7)) & 7)*8 + (p&7).
static __device__ __forceinline__ void vt_write8(ushort* vtbuf, int h0, int hsw,
                                                 int p, const short8& v) {
  const int pc = (p >> 3) ^ hsw;
  ushort* row = vtbuf + h0 * 64 + (p & 7);
#pragma unroll
  for (int u = 0; u < 8; ++u)
    row[u * 64 + (((pc ^ u) & 7) << 3)] = ((const ushort*)&v)[u];
}

// Stage a 64x64 bf16 K tile (global rows pbase..pbase+63) into kbuf via
// global_load_lds, pre-swizzled source (rule 21).
static __device__ __forceinline__ void stage_k(const ushort* kglob, int pbase,
                                               ushort* kbuf, int wave, int lane) {
  const int rl = lane >> 3;           // row within the 8-row chunk (== r&7)
  const int c = (lane & 7) ^ rl;      // inverse-swizzled source chunk
#pragma unroll
  for (int j = 0; j < 2; ++j) {
    const int ch = wave * 2 + j;
    const ushort* src = kglob + (size_t)(pbase + ch * 8 + rl) * 3072 + c * 8;
    __builtin_amdgcn_global_load_lds(
        (const __attribute__((address_space(1))) void*)src,
        (__attribute__((address_space(3))) void*)(kbuf + ch * 512), 16, 0, 0);
  }
}

// Flash causal attention, 32 q-rows per wave (two 16-row sets).
// QKV[8192][3072]: Q cols 0..1023, K 1024..2047, V 2048..3071; head h at
// sub-col h*64; row = b*2048 + pos. Z over Q in-place.
// Grid 512: xcd=id&7, g = xcd*8 + ((id>>3)&7) (8 (b,h) groups per XCD, as
// verified in R10), pairIdx = id>>6 (0..7). Block runs q-tiles of 128 rows:
// pass0 QB=pairIdx, pass1 QB=15-pairIdx; np(QB) = 2*QB+2 p-tiles ->
// total 34 iters per block, UNIFORM (R12 lesson).
// Per pass: 4 waves x 32 q-rows (set0 rows +0..63, set1 rows +64..127 within
// the q-tile; each wave owns rows wave*16+lm of each set-half).
// ka/kb read once per iter feed BOTH sets' QK; vb read once per (kc,c) feeds
// both sets' PV (interleaved, single vb live). Set0 inactive on the last
// iter of each pass (wave-uniform). l via ones-MFMA per set.
__global__ __launch_bounds__(256) void flash4_kernel(ushort* __restrict__ QKV) {
  constexpr int LD = 3072;
  __shared__ __align__(16) ushort vt[2][64 * 64];
  __shared__ __align__(16) ushort kt[2][64 * 64];
  __shared__ __align__(16) ushort pbuf[4][2][16 * 64];

  const int id = blockIdx.x;
  const int g = (id & 7) * 8 + ((id >> 3) & 7);  // (b,head) group, XCD-local
  const int pairIdx = id >> 6;                    // 0..7
  const int head = g & 15;
  const int b = g >> 4;

  const int tid = threadIdx.x;
  const int wave = tid >> 6, lane = tid & 63;
  const int lm = lane & 15, quad = lane >> 4;

  const size_t qcol = (size_t)b * 2048 * LD + head * 64;
  const size_t vcol = qcol + 2048;
  const ushort* kglob = QKV + qcol + 1024;

  const int h0 = (tid & 7) * 8;  // V staging: 8 cols per thread
  const int hsw = tid & 7;
  const int plb = tid >> 3;      // V staging p base (0..31)
  const int psw = lm & 7;        // pbuf row swizzle key
  const int ksw = lm & 7;        // kt fragment swizzle key

  constexpr float CSC = 0.180336880f;  // log2(e)/8
  const short8 vone = {0x3F80, 0x3F80, 0x3F80, 0x3F80,
                       0x3F80, 0x3F80, 0x3F80, 0x3F80};  // bf16 1.0 x8

  for (int pass = 0; pass < 2; ++pass) {
    const int QB = pass ? 15 - pairIdx : pairIdx;
    const int np = 2 * QB + 2;
    const int qrow0 = QB * 128 + wave * 16;   // set0 rows (q-tile lower half)
    const int qrow1 = qrow0 + 64;             // set1 rows (upper half)
    const int qg0 = qrow0 + lm;
    const int qg1 = qrow1 + lm;

    const ushort* qp0 = QKV + qcol + (size_t)(qrow0 + lm) * LD;
    short8 qa00 = *(const short8*)(qp0 + quad * 8);
    short8 qa01 = *(const short8*)(qp0 + 32 + quad * 8);
    const ushort* qp1 = QKV + qcol + (size_t)(qrow1 + lm) * LD;
    short8 qa10 = *(const short8*)(qp1 + quad * 8);
    short8 qa11 = *(const short8*)(qp1 + 32 + quad * 8);

    f32x4 accz0[4] = {}, accz1[4] = {};
    f32x4 lacc0 = {}, lacc1 = {};

    block_sync_lds();  // prior pass's vt/kt reads complete before restage

    stage_k(kglob, 0, kt[0], wave, lane);
#pragma unroll
    for (int rr = 0; rr < 2; ++rr) {
      const int p = plb + rr * 32;
      short8 v = *(const short8*)(QKV + vcol + (size_t)p * LD + h0);
      vt_write8(vt[0], h0, hsw, p, v);
    }

    for (int it = 0; it < np; ++it) {
      const int p0 = it * 64;
      block_sync_full();

      // K fragments (block-shared; conflict-free) — feed BOTH q-sets
      short8 ka[4], kb[4];
      const ushort* kbuf = kt[it & 1];
#pragma unroll
      for (int s = 0; s < 4; ++s) {
        const ushort* kr = kbuf + (s * 16 + lm) * 64;
        ka[s] = *(const short8*)(kr + (((quad ^ ksw) & 7) << 3));
        kb[s] = *(const short8*)(kr + ((((quad + 4) ^ ksw) & 7) << 3));
      }

      const bool more = (it + 1 < np);
      short8 nv0, nv1;
      if (more) {
        nv0 = *(const short8*)(QKV + vcol + (size_t)(p0 + 64 + plb) * LD + h0);
        nv1 = *(const short8*)(QKV + vcol + (size_t)(p0 + 96 + plb) * LD + h0);
        stage_k(kglob, p0 + 64, kt[(it + 1) & 1], wave, lane);
      }

      const bool act0 = (it < np - 1);  // set0 done before set1's diag iter

      // QK^T for both sets off the same ka/kb
      f32x4 t40[4], t41[4];
      __builtin_amdgcn_s_setprio(1);
      if (act0) {
#pragma unroll
        for (int s = 0; s < 4; ++s) {
          f32x4 t = {0.f, 0.f, 0.f, 0.f};
          t = MFMA16(ka[s], qa00, t);
          t = MFMA16(kb[s], qa01, t);
          t40[s] = t;
        }
      }
#pragma unroll
      for (int s = 0; s < 4; ++s) {
        f32x4 t = {0.f, 0.f, 0.f, 0.f};
        t = MFMA16(ka[s], qa10, t);
        t = MFMA16(kb[s], qa11, t);
        t41[s] = t;
      }
      __builtin_amdgcn_s_setprio(0);

      ushort* pw0 = &pbuf[wave][0][0] + lm * 64;
      ushort* pw1 = &pbuf[wave][1][0] + lm * 64;

      // set0 softmax + pack (diag at it == np-2)
      if (act0) {
        float ps[4][4];
        if (it != np - 2) {
#pragma unroll
          for (int s = 0; s < 4; ++s)
#pragma unroll
            for (int r = 0; r < 4; ++r)
              ps[s][r] = fexp2(t40[s][r] * CSC);
        } else {
#pragma unroll
          for (int s = 0; s < 4; ++s)
#pragma unroll
            for (int r = 0; r < 4; ++r) {
              const int pg = p0 + s * 16 + quad * 4 + r;
              const float e = fexp2(t40[s][r] * CSC);
              ps[s][r] = (pg > qg0) ? 0.f : e;
            }
        }
#pragma unroll
        for (int s = 0; s < 4; ++s) {
          uint2 pk;
          pk.x = (uint)f2bf(ps[s][0]) | ((uint)f2bf(ps[s][1]) << 16);
          pk.y = (uint)f2bf(ps[s][2]) | ((uint)f2bf(ps[s][3]) << 16);
          *(uint2*)(pw0 + ((((2 * s + (quad >> 1)) ^ psw) & 7) << 3) +
                    ((quad & 1) << 2)) = pk;
        }
      }

      // set1 softmax + pack (diag at it == np-1)
      {
        float ps[4][4];
        if (it != np - 1) {
#pragma unroll
          for (int s = 0; s < 4; ++s)
#pragma unroll
            for (int r = 0; r < 4; ++r)
              ps[s][r] = fexp2(t41[s][r] * CSC);
        } else {
#pragma unroll
          for (int s = 0; s < 4; ++s)
#pragma unroll
            for (int r = 0; r < 4; ++r) {
              const int pg = p0 + s * 16 + quad * 4 + r;
              const float e = fexp2(t41[s][r] * CSC);
              ps[s][r] = (pg > qg1) ? 0.f : e;
            }
        }
#pragma unroll
        for (int s = 0; s < 4; ++s) {
          uint2 pk;
          pk.x = (uint)f2bf(ps[s][0]) | ((uint)f2bf(ps[s][1]) << 16);
          pk.y = (uint)f2bf(ps[s][2]) | ((uint)f2bf(ps[s][3]) << 16);
          *(uint2*)(pw1 + ((((2 * s + (quad >> 1)) ^ psw) & 7) << 3) +
                    ((quad & 1) << 2)) = pk;
        }
      }

      // PV interleaved: one vb read serves both sets
      const ushort* vbuf = vt[it & 1];
      __builtin_amdgcn_s_setprio(1);
#pragma unroll
      for (int kc = 0; kc < 2; ++kc) {
        const int poff = (((kc * 4 + quad) ^ psw) & 7) << 3;
        short8 pa1v = *(const short8*)(pw1 + poff);
        short8 pa0v;
        if (act0) pa0v = *(const short8*)(pw0 + poff);
        lacc1 = MFMA16(pa1v, vone, lacc1);
        if (act0) lacc0 = MFMA16(pa0v, vone, lacc0);
#pragma unroll
        for (int c = 0; c < 4; ++c) {
          const int hrow = c * 16 + lm;
          const int fh = ((hrow >> 3) ^ hrow) & 7;
          short8 vb = *(const short8*)(
              vbuf + hrow * 64 + ((((4 * kc + quad) ^ fh) & 7) << 3));
          accz1[c] = MFMA16(pa1v, vb, accz1[c]);
          if (act0) accz0[c] = MFMA16(pa0v, vb, accz0[c]);
        }
      }
      __builtin_amdgcn_s_setprio(0);

      if (more) {
        ushort* nbuf = vt[(it + 1) & 1];
        vt_write8(nbuf, h0, hsw, plb, nv0);
        vt_write8(nbuf, h0, hsw, plb + 32, nv1);
      }
    }

    // epilogue: lacc[r] = full row-sum for q=quad*4+r; scale + write Z.
#pragma unroll
    for (int r = 0; r < 4; ++r) {
      const float inv0 = 1.f / lacc0[r];
      const float inv1 = 1.f / lacc1[r];
#pragma unroll
      for (int c = 0; c < 4; ++c) {
        QKV[qcol + (size_t)(qrow0 + quad * 4 + r) * LD + c * 16 + lm] =
            f2bf(accz0[c][r] * inv0);
        QKV[qcol + (size_t)(qrow1 + quad * 4 + r) * LD + c * 16 + lm] =
            f2bf(accz1[c][r] * inv1);
      }
    }
  }
}

extern "C" void kernel_launch(void* const* d_in, const int* in_sizes, int n_in,
                              void* d_out, int out_size, void* d_ws, size_t ws_size,
                              hipStream_t stream) {
  (void)in_sizes; (void)n_in; (void)out_size; (void)ws_size;
  const float* x  = (const float*)d_in[0];   // (4,2048,1024) = (8192,1024)
  const float* wk = (const float*)d_in[1];   // (16,64,1024) flat (1024,1024)
  const float* wq = (const float*)d_in[2];
  const float* wv = (const float*)d_in[3];
  const float* wo = (const float*)d_in[4];   // (1024,1024)
  float* out = (float*)d_out;

  const size_t WSZ = (size_t)1024 * 1024;
  ushort* wqkv_b = (ushort*)d_ws;            // rows: 0..1023 Q, 1024.. K, 2048.. V
  ushort* wo_b = wqkv_b + 3 * WSZ;
  ushort* QKV = wo_b + WSZ;                  // 8192 x 3072
  ushort* xb = (ushort*)d_out;               // bf16 x in d_out (16 of 32 MB);
                                             // dead before out-proj writes

  // Fused converts: 4*(1M/4) + (8M/4) = 3145728 float4s = 12288 blocks exact.
  convert_all_kernel<<<12288, 256, 0, stream>>>(wq, wk, wv, wo, x,
                                                wqkv_b, wo_b, xb);

  // All-batch QKV projection: 2-buffer pipelined 128x128, 2 blocks/CU.
  gemm_kernel<__hip_bfloat16><<<1536, 256, 0, stream>>>(
      xb, 1024, wqkv_b, 1024, (__hip_bfloat16*)QKV, 3072, 1024, 3);

  flash4_kernel<<<512, 256, 0, stream>>>(QKV);

  // Out projection: Z (QKV cols 0..1023) * Wo^T -> fp32 out.
  gemm_kernel<float><<<512, 256, 0, stream>>>(
      QKV, 3072, wo_b, 1024, out, 1024, 1024, 1);
}

// Round 10
// 253.780 us; speedup vs baseline: 1.1929x; 1.1929x over previous
//
#include <hip/hip_runtime.h>
#include <hip/hip_bf16.h>

// Attention forward, MI355X (gfx950). fp32 in/out, bf16 MFMA internally.
// ws (56 MB): wqkv_b[3072x1024 bf16] | wo_b[1024x1024 bf16] | QKV[8192x3072 bf16]
// xb (bf16 x) lives in d_out's first 16 MB (dead before out-proj writes).
// Dispatches: 1 fused convert; QKV GEMM (gemm3); flash; out-proj GEMM (gemm2p).
// MFMA layouts (verified m89/m74):
//   A-frag: A[m=lane&15][k=(lane>>4)*8+j]; B-frag: B[n=lane&15][k=...]
//   C/D:    col=lane&15, row=(lane>>4)*4+reg
//
// Round-8:  both-sides LDS swizzles in flash. Conflicts 1.62e7->6.5e6, dur flat.
// Round-9:  lgkm-only barrier in flash. 163->157 us.
// Round-10: K LDS-staged (pre-swizzled source) + XCD grouping in flash.
//           FETCH 240->38 MB, flash 157->89.6 us.
// Round-11: GEMM XCD remap + BK=64 swizzled staging + fused converts. 280->262.
// Round-12: fused pair p-loop: per-CU np imbalance -> 105 us. REVERTED.
// Round-13: ones-MFMA l-sum + setprio: flash 86.3, VGPR 84.
// Round-14: gemm3 QKV (128x256 3-buf counted vmcnt): total 251.0 (best).
// Round-15: gemm2p both GEMMs: 253.3 (~noise vs gemm3).
// Round-16: flash 32q/wave @ grid 512: DS savings real (conflicts -32%) but
//           occupancy 24->11 exposed the latency chain -> 132 us. REVERTED.
//           Lesson (with R12): flash is latency/occupancy-bound first; the
//           R4/R13 structure at 4 blocks/CU is converged (3 axes probed).
// Round-17 (this): restore best-known state: flash=R13, QKV=gemm3 (R7's
//   251.0 config), out-proj=gemm2p (R8). No new experiment (2 failed
//   structural bets in a row -> re-anchor the baseline).

typedef short short8 __attribute__((ext_vector_type(8)));
typedef float f32x4 __attribute__((ext_vector_type(4)));

#define MFMA16(a, b, c) __builtin_amdgcn_mfma_f32_16x16x32_bf16((a), (b), (c), 0, 0, 0)

static __device__ __forceinline__ ushort f2bf(float f) {
  union { __hip_bfloat16 h; ushort u; } cv;
  cv.h = __float2bfloat16(f);
  return cv.u;
}

static __device__ __forceinline__ float fexp2(float x) {
#if __has_builtin(__builtin_amdgcn_exp2f)
  return __builtin_amdgcn_exp2f(x);
#else
  return __expf(x * 0.69314718056f);
#endif
}

// Barrier WITHOUT any vmcnt drain: LDS writes visible, globals keep flying.
static __device__ __forceinline__ void block_sync_lds() {
  asm volatile("s_waitcnt lgkmcnt(0)" ::: "memory");
  __builtin_amdgcn_s_barrier();
  __builtin_amdgcn_sched_barrier(0);
}

// Barrier that ALSO waits outstanding globals (global_load_lds visibility).
static __device__ __forceinline__ void block_sync_full() {
  asm volatile("s_waitcnt vmcnt(0) lgkmcnt(0)" ::: "memory");
  __builtin_amdgcn_s_barrier();
  __builtin_amdgcn_sched_barrier(0);
}

static __device__ __forceinline__ void store_out(float* p, float v) { *p = v; }
static __device__ __forceinline__ void store_out(__hip_bfloat16* p, float v) {
  *p = __float2bfloat16(v);
}

// One fused convert: wq|wk|wv -> wqkv_b rows, wo -> wo_b, x -> xb.
__global__ __launch_bounds__(256) void convert_all_kernel(
    const float* __restrict__ wq, const float* __restrict__ wk,
    const float* __restrict__ wv, const float* __restrict__ wo,
    const float* __restrict__ x, ushort* __restrict__ wqkv,
    ushort* __restrict__ wob, ushort* __restrict__ xb) {
  constexpr int W4 = 262144;           // (1024*1024)/4
  constexpr size_t WSZ = (size_t)1024 * 1024;
  const int i = blockIdx.x * blockDim.x + threadIdx.x;
  const float* src;
  ushort* dst;
  int j;
  if (i < 2 * W4) {
    if (i < W4)      { src = wq; dst = wqkv;           j = i; }
    else             { src = wk; dst = wqkv + WSZ;     j = i - W4; }
  } else if (i < 4 * W4) {
    if (i < 3 * W4)  { src = wv; dst = wqkv + 2 * WSZ; j = i - 2 * W4; }
    else             { src = wo; dst = wob;            j = i - 3 * W4; }
  } else {
    src = x; dst = xb; j = i - 4 * W4;
  }
  const float4 v = ((const float4*)src)[j];
  ushort4 o;
  o.x = f2bf(v.x); o.y = f2bf(v.y); o.z = f2bf(v.z); o.w = f2bf(v.w);
  ((ushort4*)dst)[j] = o;
}

// ---------------- 2-buffer pipelined 128x128 GEMM (gemm2p, R15) ----------
// C[M,N] = A[M,K](bf16) * B[N,K]^T(bf16), OUT_T out. BK=64, 4 waves,
// wave tile 64x64, 2 LDS buffers (64 KB -> 2 blocks/CU). Counted vmcnt.
template <typename OUT_T>
__global__ __launch_bounds__(256, 2) void gemm_kernel(
    const ushort* __restrict__ A, int lda, const ushort* __restrict__ B, int ldb,
    OUT_T* __restrict__ C, int ldc, int K, int cpx) {
  __shared__ __align__(16) ushort As[2][128 * 64];
  __shared__ __align__(16) ushort Bs[2][128 * 64];
  const int tid = threadIdx.x;
  const int wave = tid >> 6, lane = tid & 63;
  const int lm = lane & 15, quad = lane >> 4;

  const int id = blockIdx.x;
  const int local = id >> 3;
  const int nt = (id & 7) * cpx + local % cpx;
  const int mt = local / cpx;
  const size_t m0 = (size_t)mt * 128;
  const size_t n0 = (size_t)nt * 128;

  const int rl = lane >> 3;        // row within 8-row staging chunk
  const int cs = (lane & 7) ^ rl;  // pre-swizzled source col-chunk
  const int fsw = lm & 7;          // fragment read swizzle key
  const int wm = (wave >> 1) * 64, wn = (wave & 1) * 64;
  const int T = K >> 6;

#pragma unroll
  for (int j = 0; j < 4; ++j) {
    const int ch = wave * 4 + j;
    __builtin_amdgcn_global_load_lds(
        (const __attribute__((address_space(1))) void*)(B + (n0 + ch * 8 + rl) * (size_t)ldb + cs * 8),
        (__attribute__((address_space(3))) void*)(Bs[0] + ch * 512), 16, 0, 0);
    __builtin_amdgcn_global_load_lds(
        (const __attribute__((address_space(1))) void*)(A + (m0 + ch * 8 + rl) * (size_t)lda + cs * 8),
        (__attribute__((address_space(3))) void*)(As[0] + ch * 512), 16, 0, 0);
  }

  f32x4 acc[4][4] = {};
  for (int t = 0; t < T; ++t) {
    const int cur = t & 1;
    if (t + 1 < T) {
      const int k0 = (t + 1) << 6;
      ushort* an = As[cur ^ 1];
      ushort* bn = Bs[cur ^ 1];
#pragma unroll
      for (int j = 0; j < 4; ++j) {
        const int ch = wave * 4 + j;
        __builtin_amdgcn_global_load_lds(
            (const __attribute__((address_space(1))) void*)(B + (n0 + ch * 8 + rl) * (size_t)ldb + k0 + cs * 8),
            (__attribute__((address_space(3))) void*)(bn + ch * 512), 16, 0, 0);
        __builtin_amdgcn_global_load_lds(
            (const __attribute__((address_space(1))) void*)(A + (m0 + ch * 8 + rl) * (size_t)lda + k0 + cs * 8),
            (__attribute__((address_space(3))) void*)(an + ch * 512), 16, 0, 0);
      }
      asm volatile("s_waitcnt vmcnt(8)" ::: "memory");
    } else {
      asm volatile("s_waitcnt vmcnt(0)" ::: "memory");
    }
    __builtin_amdgcn_s_barrier();       // barrier1: tile t visible to all
    __builtin_amdgcn_sched_barrier(0);

    short8 a[4][2], b[4][2];
    const ushort* ab = As[cur];
    const ushort* bb = Bs[cur];
#pragma unroll
    for (int i = 0; i < 4; ++i) {
      const ushort* ar = ab + (wm + i * 16 + lm) * 64;
      const ushort* br = bb + (wn + i * 16 + lm) * 64;
#pragma unroll
      for (int ks = 0; ks < 2; ++ks) {
        const int off = (((ks * 4 + quad) ^ fsw) & 7) << 3;
        a[i][ks] = *(const short8*)(ar + off);
        b[i][ks] = *(const short8*)(br + off);
      }
    }
    asm volatile("s_waitcnt lgkmcnt(0)" ::: "memory");
    __builtin_amdgcn_s_barrier();       // barrier2: all reads done
    __builtin_amdgcn_sched_barrier(0);

    __builtin_amdgcn_s_setprio(1);
#pragma unroll
    for (int i = 0; i < 4; ++i)
#pragma unroll
      for (int j = 0; j < 4; ++j)
#pragma unroll
        for (int ks = 0; ks < 2; ++ks)
          acc[i][j] = MFMA16(a[i][ks], b[j][ks], acc[i][j]);
    __builtin_amdgcn_s_setprio(0);
  }

  const int rq = quad * 4;
#pragma unroll
  for (int i = 0; i < 4; ++i)
#pragma unroll
    for (int j = 0; j < 4; ++j)
#pragma unroll
      for (int r = 0; r < 4; ++r)
        store_out(&C[(m0 + wm + i * 16 + rq + r) * (size_t)ldc + n0 + wn + j * 16 + lm],
                  acc[i][j][r]);
}

// ---------------- 128M x 256N 3-buffer pipelined GEMM (gemm3, R14) -------
static __device__ __forceinline__ void stage_part(
    const ushort* __restrict__ Ab, int lda, const ushort* __restrict__ Bb,
    int ldb, int k0, ushort* abuf, ushort* bbuf, int wave, int lane, int part) {
  const int rl = lane >> 3, c8 = lane & 7;
  const int cs = c8 ^ rl;
  if (part == 0) {
#pragma unroll
    for (int i = 0; i < 2; ++i) {
      const int r = i * 64 + wave * 8 + rl;
      __builtin_amdgcn_global_load_lds(
          (const __attribute__((address_space(1))) void*)(Ab + (size_t)r * lda + k0 + cs * 8),
          (__attribute__((address_space(3))) void*)(abuf + (i * 8 + wave) * 512), 16, 0, 0);
    }
#pragma unroll
    for (int i = 0; i < 2; ++i) {
      const int r = i * 64 + wave * 8 + rl;
      __builtin_amdgcn_global_load_lds(
          (const __attribute__((address_space(1))) void*)(Bb + (size_t)r * ldb + k0 + cs * 8),
          (__attribute__((address_space(3))) void*)(bbuf + (i * 8 + wave) * 512), 16, 0, 0);
    }
  } else {
#pragma unroll
    for (int i = 2; i < 4; ++i) {
      const int r = i * 64 + wave * 8 + rl;
      __builtin_amdgcn_global_load_lds(
          (const __attribute__((address_space(1))) void*)(Bb + (size_t)r * ldb + k0 + cs * 8),
          (__attribute__((address_space(3))) void*)(bbuf + (i * 8 + wave) * 512), 16, 0, 0);
    }
  }
}

// 512 threads = 8 waves (2M x 4N), wave tile 64x64. 3 LDS buffers (144 KB):
// stage t+2 while computing t (buffer last read in group t-1) -> race-free.
// vmcnt(6) at group boundaries only (never 0 mid-loop).
template <typename OUT_T>
__global__ __launch_bounds__(512, 2) void gemm3_kernel(
    const ushort* __restrict__ A, int lda, const ushort* __restrict__ B, int ldb,
    OUT_T* __restrict__ C, int ldc, int K) {
  __shared__ __align__(16) ushort As[3][128 * 64];
  __shared__ __align__(16) ushort Bs[3][256 * 64];

  const int tid = threadIdx.x;
  const int wave = tid >> 6, lane = tid & 63;
  const int lm = lane & 15, quad = lane >> 4;
  const int wm = wave >> 2, wn = wave & 3;

  const int id = blockIdx.x;
  const int mt = (id & 7) * 8 + ((id >> 3) & 7);
  const int nt = id >> 6;
  const size_t m0 = (size_t)mt * 128;
  const size_t n0 = (size_t)nt * 256;

  const ushort* Abase = A + m0 * (size_t)lda;
  const ushort* Bbase = B + n0 * (size_t)ldb;
  const int fsw = lm & 7;
  const int T = K >> 6;

  stage_part(Abase, lda, Bbase, ldb, 0, As[0], Bs[0], wave, lane, 0);
  stage_part(Abase, lda, Bbase, ldb, 0, As[0], Bs[0], wave, lane, 1);
  stage_part(Abase, lda, Bbase, ldb, 64, As[1], Bs[1], wave, lane, 0);
  stage_part(Abase, lda, Bbase, ldb, 64, As[1], Bs[1], wave, lane, 1);
  asm volatile("s_waitcnt vmcnt(6)" ::: "memory");
  __builtin_amdgcn_s_barrier();
  __builtin_amdgcn_sched_barrier(0);

  f32x4 acc[4][4] = {};
  int bt = 0, bs = 2;
  for (int t = 0; t < T; ++t) {
    const ushort* ab = As[bt];
    const ushort* bb = Bs[bt];
    const bool pre = (t + 2 < T);
    const int kp = (t + 2) << 6;

    // ---- phase 0: B all frags + A mf 0,1; MFMA mf 0,1 ----
    short8 bfr[4][2], a0[2][2];
#pragma unroll
    for (int nf = 0; nf < 4; ++nf) {
      const ushort* br = bb + (wn * 64 + nf * 16 + lm) * 64;
#pragma unroll
      for (int ks = 0; ks < 2; ++ks)
        bfr[nf][ks] = *(const short8*)(br + ((((ks * 4 + quad) ^ fsw) & 7) << 3));
    }
#pragma unroll
    for (int mf = 0; mf < 2; ++mf) {
      const ushort* ar = ab + (wm * 64 + mf * 16 + lm) * 64;
#pragma unroll
      for (int ks = 0; ks < 2; ++ks)
        a0[mf][ks] = *(const short8*)(ar + ((((ks * 4 + quad) ^ fsw) & 7) << 3));
    }
    if (pre) stage_part(Abase, lda, Bbase, ldb, kp, As[bs], Bs[bs], wave, lane, 0);
    asm volatile("" ::: "memory");
    __builtin_amdgcn_s_barrier();
    asm volatile("s_waitcnt lgkmcnt(0)" ::: "memory");
    __builtin_amdgcn_sched_barrier(0);
    __builtin_amdgcn_s_setprio(1);
#pragma unroll
    for (int mf = 0; mf < 2; ++mf)
#pragma unroll
      for (int nf = 0; nf < 4; ++nf)
#pragma unroll
        for (int ks = 0; ks < 2; ++ks)
          acc[mf][nf] = MFMA16(a0[mf][ks], bfr[nf][ks], acc[mf][nf]);
    __builtin_amdgcn_s_setprio(0);
    asm volatile("" ::: "memory");
    __builtin_amdgcn_s_barrier();

    // ---- phase 1: A mf 2,3; MFMA mf 2,3 (B reused from regs) ----
    short8 a1[2][2];
#pragma unroll
    for (int mf = 0; mf < 2; ++mf) {
      const ushort* ar = ab + (wm * 64 + (mf + 2) * 16 + lm) * 64;
#pragma unroll
      for (int ks = 0; ks < 2; ++ks)
        a1[mf][ks] = *(const short8*)(ar + ((((ks * 4 + quad) ^ fsw) & 7) << 3));
    }
    if (pre) stage_part(Abase, lda, Bbase, ldb, kp, As[bs], Bs[bs], wave, lane, 1);
    if (pre) asm volatile("s_waitcnt vmcnt(6)" ::: "memory");
    else     asm volatile("s_waitcnt vmcnt(0)" ::: "memory");
    __builtin_amdgcn_s_barrier();
    asm volatile("s_waitcnt lgkmcnt(0)" ::: "memory");
    __builtin_amdgcn_sched_barrier(0);
    __builtin_amdgcn_s_setprio(1);
#pragma unroll
    for (int mf = 0; mf < 2; ++mf)
#pragma unroll
      for (int nf = 0; nf < 4; ++nf)
#pragma unroll
        for (int ks = 0; ks < 2; ++ks)
          acc[mf + 2][nf] = MFMA16(a1[mf][ks], bfr[nf][ks], acc[mf + 2][nf]);
    __builtin_amdgcn_s_setprio(0);
    asm volatile("" ::: "memory");
    __builtin_amdgcn_s_barrier();

    bt = (bt == 2) ? 0 : bt + 1;
    bs = (bs == 2) ? 0 : bs + 1;
  }

#pragma unroll
  for (int mf = 0; mf < 4; ++mf)
#pragma unroll
    for (int nf = 0; nf < 4; ++nf)
#pragma unroll
      for (int r = 0; r < 4; ++r)
        store_out(&C[(m0 + wm * 64 + mf * 16 + quad * 4 + r) * (size_t)ldc +
                     n0 + wn * 64 + nf * 16 + lm],
                  acc[mf][nf][r]);
}

// Swizzled V^T LDS write: 8 cols starting at h0 for row p.
// Element (p, h) lives at h*64 + (((p>>3) ^ (h>>3) ^ (h&7)) & 7)*8 + (p&7).
static __device__ __forceinline__ void vt_write8(ushort* vtbuf, int h0, int hsw,
                                                 int p, const short8& v) {
  const int pc = (p >> 3) ^ hsw;
  ushort* row = vtbuf + h0 * 64 + (p & 7);
#pragma unroll
  for (int u = 0; u < 8; ++u)
    row[u * 64 + (((pc ^ u) & 7) << 3)] = ((const ushort*)&v)[u];
}

// Stage a 64x64 bf16 K tile into kbuf via global_load_lds (rule 21).
static __device__ __forceinline__ void stage_k(const ushort* kglob, int pbase,
                                               ushort* kbuf, int wave, int lane) {
  const int rl = lane >> 3;
  const int c = (lane & 7) ^ rl;
#pragma unroll
  for (int j = 0; j < 2; ++j) {
    const int ch = wave * 2 + j;
    const ushort* src = kglob + (size_t)(pbase + ch * 8 + rl) * 3072 + c * 8;
    __builtin_amdgcn_global_load_lds(
        (const __attribute__((address_space(1))) void*)src,
        (__attribute__((address_space(3))) void*)(kbuf + ch * 512), 16, 0, 0);
  }
}

// Flash causal attention (R13 structure, verified 86.3 us — converged).
__global__ __launch_bounds__(256) void flash4_kernel(ushort* __restrict__ QKV) {
  constexpr int LD = 3072;
  __shared__ __align__(16) ushort vt[2][64 * 64];
  __shared__ __align__(16) ushort kt[2][64 * 64];
  __shared__ __align__(16) ushort pbuf[4][16 * 64];

  const int id = blockIdx.x;
  const int g = (id & 7) * 8 + ((id >> 3) & 7);  // (b,head) group, XCD-local
  const int m = id >> 6;                          // q-pair index 0..15
  const int head = g & 15;
  const int b = g >> 4;

  const int tid = threadIdx.x;
  const int wave = tid >> 6, lane = tid & 63;
  const int lm = lane & 15, quad = lane >> 4;

  const size_t qcol = (size_t)b * 2048 * LD + head * 64;
  const size_t vcol = qcol + 2048;
  const ushort* kglob = QKV + qcol + 1024;

  const int h0 = (tid & 7) * 8;
  const int hsw = tid & 7;
  const int plb = tid >> 3;
  const int psw = lm & 7;
  const int ksw = lm & 7;

  constexpr float CSC = 0.180336880f;  // log2(e)/8
  const short8 vone = {0x3F80, 0x3F80, 0x3F80, 0x3F80,
                       0x3F80, 0x3F80, 0x3F80, 0x3F80};  // bf16 1.0 x8

  for (int pass = 0; pass < 2; ++pass) {
    const int qbi = pass ? 31 - m : m;
    const int qrow = qbi * 64 + wave * 16;
    const int qg = qrow + lm;
    const int nt = qbi + 1;

    const ushort* qp = QKV + qcol + (size_t)(qrow + lm) * LD;
    short8 qa0 = *(const short8*)(qp + quad * 8);
    short8 qa1 = *(const short8*)(qp + 32 + quad * 8);

    f32x4 accz[4] = {};
    f32x4 lacc = {};

    block_sync_lds();

    stage_k(kglob, 0, kt[0], wave, lane);
#pragma unroll
    for (int rr = 0; rr < 2; ++rr) {
      const int p = plb + rr * 32;
      short8 v = *(const short8*)(QKV + vcol + (size_t)p * LD + h0);
      vt_write8(vt[0], h0, hsw, p, v);
    }

    for (int it = 0; it < nt; ++it) {
      const int p0 = it * 64;
      block_sync_full();

      short8 ka[4], kb[4];
      const ushort* kbuf = kt[it & 1];
#pragma unroll
      for (int s = 0; s < 4; ++s) {
        const ushort* kr = kbuf + (s * 16 + lm) * 64;
        ka[s] = *(const short8*)(kr + (((quad ^ ksw) & 7) << 3));
        kb[s] = *(const short8*)(kr + ((((quad + 4) ^ ksw) & 7) << 3));
      }

      const bool more = (it + 1 < nt);
      short8 nv0, nv1;
      if (more) {
        nv0 = *(const short8*)(QKV + vcol + (size_t)(p0 + 64 + plb) * LD + h0);
        nv1 = *(const short8*)(QKV + vcol + (size_t)(p0 + 96 + plb) * LD + h0);
        stage_k(kglob, p0 + 64, kt[(it + 1) & 1], wave, lane);
      }

      f32x4 t4[4];
      __builtin_amdgcn_s_setprio(1);
#pragma unroll
      for (int s = 0; s < 4; ++s) {
        f32x4 t = {0.f, 0.f, 0.f, 0.f};
        t = MFMA16(ka[s], qa0, t);
        t = MFMA16(kb[s], qa1, t);
        t4[s] = t;
      }
      __builtin_amdgcn_s_setprio(0);

      float ps[4][4];
      if (it != nt - 1) {
#pragma unroll
        for (int s = 0; s < 4; ++s)
#pragma unroll
          for (int r = 0; r < 4; ++r)
            ps[s][r] = fexp2(t4[s][r] * CSC);
      } else {
#pragma unroll
        for (int s = 0; s < 4; ++s)
#pragma unroll
          for (int r = 0; r < 4; ++r) {
            const int pg = p0 + s * 16 + quad * 4 + r;
            const float e = fexp2(t4[s][r] * CSC);
            ps[s][r] = (pg > qg) ? 0.f : e;
          }
      }

      ushort* pw = pbuf[wave] + lm * 64;
#pragma unroll
      for (int s = 0; s < 4; ++s) {
        uint2 pk;
        pk.x = (uint)f2bf(ps[s][0]) | ((uint)f2bf(ps[s][1]) << 16);
        pk.y = (uint)f2bf(ps[s][2]) | ((uint)f2bf(ps[s][3]) << 16);
        *(uint2*)(pw + ((((2 * s + (quad >> 1)) ^ psw) & 7) << 3) +
                  ((quad & 1) << 2)) = pk;
      }

      const ushort* vbuf = vt[it & 1];
      __builtin_amdgcn_s_setprio(1);
#pragma unroll
      for (int kc = 0; kc < 2; ++kc) {
        short8 pa = *(const short8*)(pw + ((((kc * 4 + quad) ^ psw) & 7) << 3));
        lacc = MFMA16(pa, vone, lacc);
#pragma unroll
        for (int c = 0; c < 4; ++c) {
          const int hrow = c * 16 + lm;
          const int fh = ((hrow >> 3) ^ hrow) & 7;
          short8 vb = *(const short8*)(
              vbuf + hrow * 64 + ((((4 * kc + quad) ^ fh) & 7) << 3));
          accz[c] = MFMA16(pa, vb, accz[c]);
        }
      }
      __builtin_amdgcn_s_setprio(0);

      if (more) {
        ushort* nbuf = vt[(it + 1) & 1];
        vt_write8(nbuf, h0, hsw, plb, nv0);
        vt_write8(nbuf, h0, hsw, plb + 32, nv1);
      }
    }

#pragma unroll
    for (int r = 0; r < 4; ++r) {
      const float inv = 1.f / lacc[r];
#pragma unroll
      for (int c = 0; c < 4; ++c)
        QKV[qcol + (size_t)(qrow + quad * 4 + r) * LD + c * 16 + lm] =
            f2bf(accz[c][r] * inv);
    }
  }
}

extern "C" void kernel_launch(void* const* d_in, const int* in_sizes, int n_in,
                              void* d_out, int out_size, void* d_ws, size_t ws_size,
                              hipStream_t stream) {
  (void)in_sizes; (void)n_in; (void)out_size; (void)ws_size;
  const float* x  = (const float*)d_in[0];   // (4,2048,1024) = (8192,1024)
  const float* wk = (const float*)d_in[1];   // (16,64,1024) flat (1024,1024)
  const float* wq = (const float*)d_in[2];
  const float* wv = (const float*)d_in[3];
  const float* wo = (const float*)d_in[4];   // (1024,1024)
  float* out = (float*)d_out;

  const size_t WSZ = (size_t)1024 * 1024;
  ushort* wqkv_b = (ushort*)d_ws;            // rows: 0..1023 Q, 1024.. K, 2048.. V
  ushort* wo_b = wqkv_b + 3 * WSZ;
  ushort* QKV = wo_b + WSZ;                  // 8192 x 3072
  ushort* xb = (ushort*)d_out;               // bf16 x in d_out (16 of 32 MB);
                                             // dead before out-proj writes

  // Fused converts: 4*(1M/4) + (8M/4) = 3145728 float4s = 12288 blocks exact.
  convert_all_kernel<<<12288, 256, 0, stream>>>(wq, wk, wv, wo, x,
                                                wqkv_b, wo_b, xb);

  // All-batch QKV projection: gemm3 (R7's 251.0-us config).
  gemm3_kernel<__hip_bfloat16><<<768, 512, 0, stream>>>(
      xb, 1024, wqkv_b, 1024, (__hip_bfloat16*)QKV, 3072, 1024);

  flash4_kernel<<<1024, 256, 0, stream>>>(QKV);

  // Out projection: Z (QKV cols 0..1023) * Wo^T -> fp32 out (gemm2p).
  gemm_kernel<float><<<512, 256, 0, stream>>>(
      QKV, 3072, wo_b, 1024, out, 1024, 1024, 1);
}